// Round 1
// baseline (427.727 us; speedup 1.0000x reference)
//
#include <hip/hip_runtime.h>

#define MM    12
#define TSOL  64
#define NXX   256
#define NYY   256
#define NTT   50
#define NOUTT 256
#define IPB   4     // output rows (i) per block (amortizes table loads)

// Per-(m,k) interpolation table, packed: .x = w0 = w*(1-ty), .y = w1 = w*ty,
// .z = iy as int bits. One 16B coalesced load per (m, lane).
__device__ float4 g_tab[MM * NOUTT];

// grid: MM blocks x 256 threads. Block m computes table row m.
__global__ __launch_bounds__(256) void ai_setup_kernel(
    const float* __restrict__ params,
    const float* __restrict__ Wq, const float* __restrict__ bq,
    const float* __restrict__ Wk, const float* __restrict__ bk)
{
    const int k = threadIdx.x;
    const int m = blockIdx.x;

    __shared__ float s_attn[MM][4];
    __shared__ float s_sw[MM];
    __shared__ float s_wm;
    __shared__ float s_ys[NYY];

    if (k < MM) {
        float ly = params[k * 3 + 0];
        float p0 = (ly - 30.0f) / 90.0f;
        float p1 = params[k * 3 + 1] / 0.0029f;
        float p2 = params[k * 3 + 2] / 0.0018f;
        const float t0 = 0.5f;                 // (75-30)/90 exact
        const float t1 = 0.001f / 0.0029f;
        const float t2 = 0.0001f / 0.0018f;
        for (int h = 0; h < 4; ++h) {
            float acc = 0.0f;
            for (int d = 0; d < 8; ++d) {
                int o = h * 8 + d;
                float q  = t0 * Wq[o * 3 + 0] + t1 * Wq[o * 3 + 1] + t2 * Wq[o * 3 + 2] + bq[o];
                float kv = p0 * Wk[o * 3 + 0] + p1 * Wk[o * 3 + 1] + p2 * Wk[o * 3 + 2] + bk[o];
                acc += kv * q;
            }
            s_attn[k][h] = acc * 0.35355339059327373f;  // 1/sqrt(8)
        }
        float d0 = (p0 - t0) / 0.25f;
        float d1 = (p1 - t1) / 0.25f;
        float d2 = (p2 - t2) / 0.25f;
        s_sw[k] = expf(-(d0 * d0 + d1 * d1 + d2 * d2) * 0.5f);
    }
    __syncthreads();

    if (k == 0) {
        float aw[MM];
        for (int j = 0; j < MM; ++j) aw[j] = 0.0f;
        for (int h = 0; h < 4; ++h) {               // softmax over m, per head
            float mx = s_attn[0][h];
            for (int j = 1; j < MM; ++j) mx = fmaxf(mx, s_attn[j][h]);
            float e[MM]; float sum = 0.0f;
            for (int j = 0; j < MM; ++j) { e[j] = expf(s_attn[j][h] - mx); sum += e[j]; }
            for (int j = 0; j < MM; ++j) aw[j] += e[j] / sum;
        }
        float swsum = 0.0f;
        for (int j = 0; j < MM; ++j) swsum += s_sw[j];
        float wj[MM]; float wsum = 0.0f;
        for (int j = 0; j < MM; ++j) {
            wj[j] = (aw[j] * 0.25f) * (s_sw[j] / swsum);
            wsum += wj[j];
        }
        s_wm = wj[m] / wsum;
    }

    // ys row for this m — EXACT fp32 op sequence of the reference:
    // ys[j] = fl( fl(l01[j]*ly) * fl(75/ly) ),  l01[j] = fl(j * fl(1/255))
    {
        float ly  = params[m * 3 + 0];
        float inv = 75.0f / ly;                    // IEEE divide (no fast-math)
        float l01 = (float)k * (1.0f / 255.0f);
        s_ys[k] = (l01 * ly) * inv;
    }
    __syncthreads();

    float w  = s_wm;
    float yq = (float)k * (75.0f / 255.0f);        // rounds to exactly 75.0 at k=255
    // upper_bound: largest j with ys[j] <= yq  (== searchsorted 'right' - 1)
    int l = 0, r = NYY;
    while (l < r) { int mid = (l + r) >> 1; if (s_ys[mid] <= yq) l = mid + 1; else r = mid; }
    int iy = l - 1;
    iy = iy < 0 ? 0 : (iy > NYY - 2 ? NYY - 2 : iy);
    float ty  = (yq - s_ys[iy]) / (s_ys[iy + 1] - s_ys[iy]);
    bool  inb = (yq >= s_ys[0]) && (yq <= s_ys[NYY - 1]);   // the k=255 knife edge
    float4 tb;
    tb.x = inb ? w * (1.0f - ty) : 0.0f;
    tb.y = inb ? w * ty          : 0.0f;
    tb.z = __int_as_float(iy);
    tb.w = 0.0f;
    g_tab[m * NOUTT + k] = tb;
}

// grid: (NOUTT/IPB, NTT), block 256.
// No LDS, no barrier: the gather index iy[m][k] ~= k (ys is near-identity up
// to fp rounding), so a wave's 64 lanes touch a contiguous ~260B span per
// load — the per-instruction coalescer makes these as cheap as coalesced
// loads. 48 independent dword loads per thread per row stay in flight
// (fine-grained vmcnt, no vmcnt(0) barrier drain), and occupancy is no
// longer capped by 48KB LDS.
__global__ __launch_bounds__(256) void ai_resample_kernel(
    const float* __restrict__ c1, const float* __restrict__ c2,
    float* __restrict__ out)
{
    const int tid = threadIdx.x;
    const int t   = blockIdx.y;
    const int i0  = blockIdx.x * IPB;
    int tsrc = (t * TSOL) / (NTT - 1);         // floor(t*64/49), fp-robust
    if (tsrc > TSOL - 1) tsrc = TSOL - 1;

    // Per-(m,k) tables: 12 coalesced 16B loads, reused across IPB rows.
    float w0[MM], w1[MM];
    unsigned int iy[MM];
#pragma unroll
    for (int m = 0; m < MM; ++m) {
        float4 tb = g_tab[m * NOUTT + tid];
        w0[m] = tb.x;
        w1[m] = tb.y;
        iy[m] = (unsigned int)__float_as_int(tb.z);
    }

    // Row-base offsets (32-bit: max index ~50.3M < 2^31), shared across lanes.
    unsigned int rbase[MM];
#pragma unroll
    for (int m = 0; m < MM; ++m)
        rbase[m] = (((unsigned int)(m * TSOL + tsrc) * NXX) + (unsigned int)i0) * NYY + iy[m];

#pragma unroll 2
    for (int r = 0; r < IPB; ++r) {
        float acc1 = 0.0f, acc2 = 0.0f;
#pragma unroll
        for (int m = 0; m < MM; ++m) {
            unsigned int off = rbase[m] + (unsigned int)r * NYY;
            float a0 = c1[off], a1 = c1[off + 1];
            float b0 = c2[off], b1 = c2[off + 1];
            acc1 += w0[m] * a0 + w1[m] * a1;
            acc2 += w0[m] * b0 + w1[m] * b1;
        }
        int i = i0 + r;
        float o1 = (tid == 0)         ? 0.001f  : acc1;  // c1[:,:,0]  = C_CU_TARGET
        float o2 = (tid == NOUTT - 1) ? 0.0001f : acc2;  // c2[:,:,-1] = C_NI_TARGET
        out[((size_t)t * NOUTT + (size_t)i) * NOUTT + (size_t)tid] = o1;
        out[((size_t)(NTT + t) * NOUTT + (size_t)i) * NOUTT + (size_t)tid] = o2;
    }
}

extern "C" void kernel_launch(void* const* d_in, const int* in_sizes, int n_in,
                              void* d_out, int out_size, void* d_ws, size_t ws_size,
                              hipStream_t stream) {
    const float* params = (const float*)d_in[0];
    const float* c1     = (const float*)d_in[1];
    const float* c2     = (const float*)d_in[2];
    const float* Wq     = (const float*)d_in[3];
    const float* bq     = (const float*)d_in[4];
    const float* Wk     = (const float*)d_in[5];
    const float* bk     = (const float*)d_in[6];
    float* out = (float*)d_out;

    ai_setup_kernel<<<dim3(MM), dim3(256), 0, stream>>>(params, Wq, bq, Wk, bk);
    ai_resample_kernel<<<dim3(NOUTT / IPB, NTT), dim3(256), 0, stream>>>(c1, c2, out);
}

// Round 2
// 403.604 us; speedup vs baseline: 1.0598x; 1.0598x over previous
//
#include <hip/hip_runtime.h>

#define MM    12
#define TSOL  64
#define NXX   256
#define NYY   256
#define NTT   50
#define NOUTT 256

// 3-tap stencil tables. For output k, out = wm1[k]*src[k-1] + wc[k]*src[k]
// + wp1[k]*src[k+1]. Valid because iy[m][k] in {k-1, k} (ys is j*(75/255)
// up to 2 ulp, so searchsorted lands at k or k+1 -- see setup kernel).
__device__ float g_wm1[MM * NOUTT];
__device__ float g_wc [MM * NOUTT];
__device__ float g_wp1[MM * NOUTT];

// grid: MM blocks x 256 threads. Block m computes table row m.
__global__ __launch_bounds__(256) void ai_setup_kernel(
    const float* __restrict__ params,
    const float* __restrict__ Wq, const float* __restrict__ bq,
    const float* __restrict__ Wk, const float* __restrict__ bk)
{
    const int k = threadIdx.x;
    const int m = blockIdx.x;

    __shared__ float s_attn[MM][4];
    __shared__ float s_sw[MM];
    __shared__ float s_wm;
    __shared__ float s_ys[NYY];

    if (k < MM) {
        float ly = params[k * 3 + 0];
        float p0 = (ly - 30.0f) / 90.0f;
        float p1 = params[k * 3 + 1] / 0.0029f;
        float p2 = params[k * 3 + 2] / 0.0018f;
        const float t0 = 0.5f;                 // (75-30)/90 exact
        const float t1 = 0.001f / 0.0029f;
        const float t2 = 0.0001f / 0.0018f;
        for (int h = 0; h < 4; ++h) {
            float acc = 0.0f;
            for (int d = 0; d < 8; ++d) {
                int o = h * 8 + d;
                float q  = t0 * Wq[o * 3 + 0] + t1 * Wq[o * 3 + 1] + t2 * Wq[o * 3 + 2] + bq[o];
                float kv = p0 * Wk[o * 3 + 0] + p1 * Wk[o * 3 + 1] + p2 * Wk[o * 3 + 2] + bk[o];
                acc += kv * q;
            }
            s_attn[k][h] = acc * 0.35355339059327373f;  // 1/sqrt(8)
        }
        float d0 = (p0 - t0) / 0.25f;
        float d1 = (p1 - t1) / 0.25f;
        float d2 = (p2 - t2) / 0.25f;
        s_sw[k] = expf(-(d0 * d0 + d1 * d1 + d2 * d2) * 0.5f);
    }
    __syncthreads();

    if (k == 0) {
        float aw[MM];
        for (int j = 0; j < MM; ++j) aw[j] = 0.0f;
        for (int h = 0; h < 4; ++h) {               // softmax over m, per head
            float mx = s_attn[0][h];
            for (int j = 1; j < MM; ++j) mx = fmaxf(mx, s_attn[j][h]);
            float e[MM]; float sum = 0.0f;
            for (int j = 0; j < MM; ++j) { e[j] = expf(s_attn[j][h] - mx); sum += e[j]; }
            for (int j = 0; j < MM; ++j) aw[j] += e[j] / sum;
        }
        float swsum = 0.0f;
        for (int j = 0; j < MM; ++j) swsum += s_sw[j];
        float wj[MM]; float wsum = 0.0f;
        for (int j = 0; j < MM; ++j) {
            wj[j] = (aw[j] * 0.25f) * (s_sw[j] / swsum);
            wsum += wj[j];
        }
        s_wm = wj[m] / wsum;
    }

    // ys row for this m — EXACT fp32 op sequence of the reference:
    // ys[j] = fl( fl(l01[j]*ly) * fl(75/ly) ),  l01[j] = fl(j * fl(1/255))
    {
        float ly  = params[m * 3 + 0];
        float inv = 75.0f / ly;                    // IEEE divide (no fast-math)
        float l01 = (float)k * (1.0f / 255.0f);
        s_ys[k] = (l01 * ly) * inv;
    }
    __syncthreads();

    float w  = s_wm;
    float yq = (float)k * (75.0f / 255.0f);        // rounds to exactly 75.0 at k=255
    // upper_bound: largest j with ys[j] <= yq  (== searchsorted 'right' - 1)
    int l = 0, r = NYY;
    while (l < r) { int mid = (l + r) >> 1; if (s_ys[mid] <= yq) l = mid + 1; else r = mid; }
    int iy = l - 1;
    iy = iy < 0 ? 0 : (iy > NYY - 2 ? NYY - 2 : iy);
    float ty  = (yq - s_ys[iy]) / (s_ys[iy + 1] - s_ys[iy]);
    bool  inb = (yq >= s_ys[0]) && (yq <= s_ys[NYY - 1]);   // the k=255 knife edge
    float a = inb ? w * (1.0f - ty) : 0.0f;        // weight on src[iy]
    float b = inb ? w * ty          : 0.0f;        // weight on src[iy+1]
    // ys monotone ~ k*(75/255)*(1 +- 2ulp) => iy is exactly k or k-1
    // (clip at k=255 gives 254 = k-1). Expand to fixed 3-tap stencil:
    bool sel = (iy == k);                          // taps (0,a,b) else (a,b,0)
    g_wm1[m * NOUTT + k] = sel ? 0.0f : a;
    g_wc [m * NOUTT + k] = sel ? a    : b;
    g_wp1[m * NOUTT + k] = sel ? b    : 0.0f;
}

// grid: (NOUTT/4, NTT), block 256 = 4 waves. Wave wv computes output row
// i = 4*blockIdx.x + wv, all 256 k's: lane l holds k = 4l..4l+3.
// Every source access is a coalesced dwordx4 (1 KB/wave/row); the +-1
// stencil neighbors come from two __shfl ops. No gathers, no LDS.
__global__ __launch_bounds__(256) void ai_resample_kernel(
    const float* __restrict__ c1, const float* __restrict__ c2,
    float* __restrict__ out)
{
    const int tid  = threadIdx.x;
    const int lane = tid & 63;
    const int wv   = tid >> 6;
    const int t    = blockIdx.y;
    const int i    = blockIdx.x * 4 + wv;
    int tsrc = (t * TSOL) / (NTT - 1);         // floor(t*64/49), fp-robust
    if (tsrc > TSOL - 1) tsrc = TSOL - 1;
    const int k0 = lane * 4;

    float4 acc1 = {0.f, 0.f, 0.f, 0.f};
    float4 acc2 = {0.f, 0.f, 0.f, 0.f};

#pragma unroll
    for (int m = 0; m < MM; ++m) {
        const float4 wm1 = *(const float4*)&g_wm1[m * NOUTT + k0];
        const float4 wc  = *(const float4*)&g_wc [m * NOUTT + k0];
        const float4 wp1 = *(const float4*)&g_wp1[m * NOUTT + k0];
        const size_t base = ((size_t)(m * TSOL + tsrc) * NXX + (size_t)i) * NYY
                          + (size_t)k0;
        float4 s1 = *(const float4*)(c1 + base);
        float4 s2 = *(const float4*)(c2 + base);

        float l1 = __shfl_up(s1.w, 1);         // src[k0-1] (lane0: weight 0)
        float r1 = __shfl_down(s1.x, 1);       // src[k0+4] (lane63: weight 0)
        acc1.x += wm1.x * l1   + wc.x * s1.x + wp1.x * s1.y;
        acc1.y += wm1.y * s1.x + wc.y * s1.y + wp1.y * s1.z;
        acc1.z += wm1.z * s1.y + wc.z * s1.z + wp1.z * s1.w;
        acc1.w += wm1.w * s1.z + wc.w * s1.w + wp1.w * r1;

        float l2 = __shfl_up(s2.w, 1);
        float r2 = __shfl_down(s2.x, 1);
        acc2.x += wm1.x * l2   + wc.x * s2.x + wp1.x * s2.y;
        acc2.y += wm1.y * s2.x + wc.y * s2.y + wp1.y * s2.z;
        acc2.z += wm1.z * s2.y + wc.z * s2.z + wp1.z * s2.w;
        acc2.w += wm1.w * s2.z + wc.w * s2.w + wp1.w * r2;
    }

    if (lane == 0)  acc1.x = 0.001f;           // c1[:,:,0]  = C_CU_TARGET
    if (lane == 63) acc2.w = 0.0001f;          // c2[:,:,-1] = C_NI_TARGET

    *(float4*)&out[((size_t)t * NOUTT + (size_t)i) * NOUTT + (size_t)k0] = acc1;
    *(float4*)&out[((size_t)(NTT + t) * NOUTT + (size_t)i) * NOUTT + (size_t)k0] = acc2;
}

extern "C" void kernel_launch(void* const* d_in, const int* in_sizes, int n_in,
                              void* d_out, int out_size, void* d_ws, size_t ws_size,
                              hipStream_t stream) {
    const float* params = (const float*)d_in[0];
    const float* c1     = (const float*)d_in[1];
    const float* c2     = (const float*)d_in[2];
    const float* Wq     = (const float*)d_in[3];
    const float* bq     = (const float*)d_in[4];
    const float* Wk     = (const float*)d_in[5];
    const float* bk     = (const float*)d_in[6];
    float* out = (float*)d_out;

    ai_setup_kernel<<<dim3(MM), dim3(256), 0, stream>>>(params, Wq, bq, Wk, bk);
    ai_resample_kernel<<<dim3(NOUTT / 4, NTT), dim3(256), 0, stream>>>(c1, c2, out);
}